// Round 14
// baseline (201.213 us; speedup 1.0000x reference)
//
#include <hip/hip_runtime.h>

// Problem constants (fixed shapes from reference)
#define NE    1024
#define CDIM  64
#define BDIM  16
#define HDIM  64
#define WDIM  64
#define NPOS  (BDIM*HDIM*WDIM)          // 65536 positions
#define ZTOT  (BDIM*CDIM*HDIM*WDIM)     // 4194304 elements

// d_out offsets (float elements), concat in reference return order
#define ZQ_OFF   0
#define LOSS_OFF 4194304
#define IDX_OFF  4194305
#define EMB_OFF  4259841
#define CS_OFF   4325377
#define EA_OFF   4326401

// monotone float->uint mapping: a<b  <=>  ordf(a)<ordf(b)
__device__ __forceinline__ unsigned ordf(float x) {
    unsigned b = __float_as_uint(x);
    return (b & 0x80000000u) ? ~b : (b | 0x80000000u);
}

__device__ __forceinline__ unsigned long long umax64(unsigned long long a,
                                                     unsigned long long b) {
    return a > b ? a : b;
}

// ---------------- K0: codebook norms (-0.5||e||^2) + transpose embT[c][j] ----------------
// 256 blocks x 256 threads: wave = one code row j, lane = channel c.
// embT write is a one-time 256KB scatter (L2-absorbed, ~2-3us).
__global__ __launch_bounds__(256) void k_enorm(const float* __restrict__ emb,
                                               float* __restrict__ en2,
                                               float* __restrict__ embT) {
    int wid  = (blockIdx.x * blockDim.x + threadIdx.x) >> 6;   // row 0..1023
    int lane = threadIdx.x & 63;
    if (wid >= NE) return;
    float v = emb[wid * CDIM + lane];
    embT[lane * NE + wid] = v;                  // transposed copy
    float s = v * v;
    #pragma unroll
    for (int off = 32; off > 0; off >>= 1) s += __shfl_xor(s, off);
    if (lane == 0) en2[wid] = -0.5f * s;
}

// ---------------- K1: fused argmin GEMM (8x8 lane tile, split-pipe operands) ----------------
// Grid: 1024 blocks (one bh row = 64 positions) x 256 threads (4 waves)
// -> 4 blocks/CU, 4 waves/SIMD (grid no longer caps occupancy at 2 blocks).
// Wave q scans codes [256q, 256q+256) in four 64-code tiles.
// Lane (lr,lc): 8 positions (lr*8..+7) x 8 codes (lc*8 within tile).
// Operand split across pipes: z from LDS (2 ds_read_b128 -> 64 B/cyc/CU,
// under the ~85 ceiling; R6 used 128 -> LDS-bound 58%) + E from global
// embT[c][j] (2 dwordx4 -> 32 B/cyc via L1/L2-hot codebook).
// Live regs ~115 (acc 64 + dbuf 32 + best/bid 16) <= 128 cap of
// launch_bounds(256,4) -> no spill (R6's 8x8 fit at VGPR=88).
// Argmin key=(ord(m)<<32)|(1023-j) => max-m-then-min-j == first-argmin.
// Same c-ascending fma chain per (p,j) + same acc+en2 fold as R6 (absmax
// 0.0) -> identical indices.
__global__ __launch_bounds__(256, 4) void k_fused5(const float* __restrict__ z,
                                                   const float* __restrict__ emb,
                                                   const float* __restrict__ embT,
                                                   const float* __restrict__ en2,
                                                   float* __restrict__ out,
                                                   float* __restrict__ lossacc) {
    __shared__ float zs[64 * 64];             // 16 KB [c][w]
    __shared__ unsigned long long keyL[64];   // per-position argmin key
    __shared__ float lred[4];

    const int t    = threadIdx.x;
    const int lane = t & 63;
    const int q    = t >> 6;          // wave 0..3 (code quarter)
    const int lr   = lane >> 3;       // 0..7 position octet
    const int lc   = lane & 7;        // 0..7 code octet
    const int bh   = blockIdx.x;      // 0..1023
    const int b    = bh >> 6;
    const int h    = bh & 63;
    const float* __restrict__ zrow = z + (size_t)b * (CDIM * HDIM * WDIM) + h * WDIM;

    if (t < 64) keyL[t] = 0ull;

    // ---- stage zs[c][w] once: thread (c = t>>2, tw = t&3) loads 4 float4 ----
    {
        const int c  = t >> 2;
        const int tw = t & 3;
        #pragma unroll
        for (int k = 0; k < 4; ++k) {
            const int f4 = k * 4 + tw;
            *(float4*)&zs[c * 64 + f4 * 4] =
                *(const float4*)(zrow + (size_t)c * (HDIM * WDIM) + f4 * 4);
        }
    }
    __syncthreads();

    const int jb0 = q * 256 + lc * 8;     // + jt*64 per tile
    float best[8];
    int   bid[8];
    #pragma unroll
    for (int p = 0; p < 8; ++p) { best[p] = -3.4e38f; bid[p] = 0; }

    const float* __restrict__ zl = &zs[lr * 8];

    #define FMA8(P, ZV, E0, E1) \
        acc[P][0] = fmaf(ZV, E0.x, acc[P][0]); \
        acc[P][1] = fmaf(ZV, E0.y, acc[P][1]); \
        acc[P][2] = fmaf(ZV, E0.z, acc[P][2]); \
        acc[P][3] = fmaf(ZV, E0.w, acc[P][3]); \
        acc[P][4] = fmaf(ZV, E1.x, acc[P][4]); \
        acc[P][5] = fmaf(ZV, E1.y, acc[P][5]); \
        acc[P][6] = fmaf(ZV, E1.z, acc[P][6]); \
        acc[P][7] = fmaf(ZV, E1.w, acc[P][7]);
    #define COMP(Z0, Z1, E0, E1) do { \
        FMA8(0, Z0.x, E0, E1) FMA8(1, Z0.y, E0, E1) \
        FMA8(2, Z0.z, E0, E1) FMA8(3, Z0.w, E0, E1) \
        FMA8(4, Z1.x, E0, E1) FMA8(5, Z1.y, E0, E1) \
        FMA8(6, Z1.z, E0, E1) FMA8(7, Z1.w, E0, E1) } while (0)

    #pragma unroll 1
    for (int jt = 0; jt < 4; ++jt) {
        const int jb = jb0 + jt * 64;              // global code base for lane
        const float* __restrict__ ep = embT + jb;  // + c*NE per channel

        float acc[8][8];
        #pragma unroll
        for (int p = 0; p < 8; ++p)
            #pragma unroll
            for (int j = 0; j < 8; ++j) acc[p][j] = 0.f;

        float4 zA0, zA1, eA0, eA1, zB0, zB1, eB0, eB1;
        zA0 = *(const float4*)(zl);
        zA1 = *(const float4*)(zl + 4);
        eA0 = *(const float4*)(ep);
        eA1 = *(const float4*)(ep + 4);

        #pragma unroll 1
        for (int c = 0; c < 64; c += 2) {
            zB0 = *(const float4*)(zl + (c + 1) * 64);
            zB1 = *(const float4*)(zl + (c + 1) * 64 + 4);
            eB0 = *(const float4*)(ep + (size_t)(c + 1) * NE);
            eB1 = *(const float4*)(ep + (size_t)(c + 1) * NE + 4);
            COMP(zA0, zA1, eA0, eA1);
            if (c + 2 < 64) {
                zA0 = *(const float4*)(zl + (c + 2) * 64);
                zA1 = *(const float4*)(zl + (c + 2) * 64 + 4);
                eA0 = *(const float4*)(ep + (size_t)(c + 2) * NE);
                eA1 = *(const float4*)(ep + (size_t)(c + 2) * NE + 4);
            }
            COMP(zB0, zB1, eB0, eB1);
        }

        // ---- fold argmin for this tile ----
        float4 n0 = *(const float4*)(en2 + jb);
        float4 n1 = *(const float4*)(en2 + jb + 4);
        #pragma unroll
        for (int p = 0; p < 8; ++p) {
            #define TRY(J, NV) { float m = acc[p][J] + NV; \
                if (m > best[p]) { best[p] = m; bid[p] = jb + J; } }
            TRY(0, n0.x) TRY(1, n0.y) TRY(2, n0.z) TRY(3, n0.w)
            TRY(4, n1.x) TRY(5, n1.y) TRY(6, n1.z) TRY(7, n1.w)
            #undef TRY
        }
    }
    #undef FMA8
    #undef COMP

    // ---- merge across the 8 lc-lanes, then across waves via LDS atomicMax ----
    #pragma unroll
    for (int p = 0; p < 8; ++p) {
        unsigned long long key =
            ((unsigned long long)ordf(best[p]) << 32) | (unsigned)(1023 - bid[p]);
        key = umax64(key, __shfl_xor(key, 1));
        key = umax64(key, __shfl_xor(key, 2));
        key = umax64(key, __shfl_xor(key, 4));
        if (lc == 0) atomicMax(&keyL[lr * 8 + p], key);
    }
    __syncthreads();

    // ---- emit: idx, z_q (straight-through), loss ----
    {
        const int w       = t & 63;          // position
        const int quarter = t >> 6;          // c-quarter 0..3
        const int bx = 1023 - (int)(unsigned)(keyL[w] & 0xFFFFFFFFull);

        if (quarter == 0) out[IDX_OFF + bh * 64 + w] = (float)bx;

        const float4* ev = (const float4*)(emb + (size_t)bx * CDIM + quarter * 16);
        float* zqrow = out + ZQ_OFF + (size_t)b * (CDIM * HDIM * WDIM) + h * WDIM + w;

        float lsum = 0.f;
        #pragma unroll
        for (int k4 = 0; k4 < 4; ++k4) {
            float4 e4 = ev[k4];
            #pragma unroll
            for (int k = 0; k < 4; ++k) {
                const int c = quarter * 16 + k4 * 4 + k;
                float zv = zs[c * 64 + w];
                float evv = (k == 0) ? e4.x : (k == 1) ? e4.y
                          : (k == 2) ? e4.z : e4.w;
                float df = evv - zv;
                zqrow[(size_t)c * (HDIM * WDIM)] = zv + df;   // z + (z_q - z)
                lsum = fmaf(df, df, lsum);
            }
        }

        #pragma unroll
        for (int off = 32; off > 0; off >>= 1) lsum += __shfl_xor(lsum, off);
        if ((t & 63) == 0) lred[t >> 6] = lsum;
        __syncthreads();
        if (t == 0)
            atomicAdd(lossacc, (lred[0] + lred[1]) + (lred[2] + lred[3]));
    }
}

// ---------------- K1b: esum/counts partials, channel x position-slice ----------------
__global__ __launch_bounds__(1024) void k_scatter(const float* __restrict__ z,
                                                  const float* __restrict__ idxf,
                                                  float* __restrict__ epart,
                                                  float* __restrict__ cntp,
                                                  int nslice) {
    __shared__ float accJ[NE];
    __shared__ float cntJ[NE];

    const int t = threadIdx.x;
    const int c = blockIdx.x & 63;
    const int s = blockIdx.x >> 6;
    accJ[t] = 0.f;
    cntJ[t] = 0.f;
    __syncthreads();

    const bool do_cnt = (c == 0);
    const int per = NPOS / nslice;
    const int p0  = s * per;
    for (int k = 0; k < per; k += 1024) {
        const int p = p0 + k + t;
        const int j = (int)idxf[p];                    // exact for 0..1023
        const int b = p >> 12, hw = p & 4095;
        const float zv = z[(size_t)b * (CDIM * HDIM * WDIM) + c * (HDIM * WDIM) + hw];
        atomicAdd(&accJ[j], zv);                       // ds_add_f32
        if (do_cnt) atomicAdd(&cntJ[j], 1.0f);
    }
    __syncthreads();

    epart[(size_t)s * (NE * CDIM) + t * CDIM + c] = accJ[t];
    if (do_cnt) cntp[s * NE + t] = cntJ[t];
}

// ---------------- K2: cluster-size EMA + n-sum + loss ----------------
__global__ __launch_bounds__(1024) void k_cluster(const float* __restrict__ cs_in,
                                                  const float* __restrict__ cntp,
                                                  const float* __restrict__ lossacc,
                                                  float* __restrict__ out,
                                                  float* __restrict__ csn,
                                                  int nslice) {
    __shared__ float red[NE];
    int j = threadIdx.x;
    float cnt = 0.f;
    for (int s = 0; s < nslice; ++s) cnt += cntp[s * NE + j];   // exact ints
    float ncs = 0.99f * cs_in[j] + 0.01f * cnt;
    out[CS_OFF + j] = ncs;
    red[j] = ncs;
    __syncthreads();
    #pragma unroll
    for (int s = 512; s > 0; s >>= 1) {
        if (j < s) red[j] += red[j + s];
        __syncthreads();
    }
    float n = red[0];
    float cs = ((ncs + 1e-5f) / (n + 0.01024f)) * n;   // (ncs+eps)/(n+NE*eps)*n
    csn[j] = cs;
    if (j == 0) out[LOSS_OFF] = 0.25f * (lossacc[0] * (1.0f / (float)ZTOT));
}

// ---------------- K3: embed_avg EMA + normalized embedding ----------------
__global__ __launch_bounds__(256) void k_embed(const float* __restrict__ ea_in,
                                               const float* __restrict__ epart,
                                               const float* __restrict__ csn,
                                               float* __restrict__ out,
                                               int nslice) {
    int i = blockIdx.x * 256 + threadIdx.x;   // 0..65535
    float es = 0.f;
    for (int s = 0; s < nslice; ++s) es += epart[(size_t)s * (NE * CDIM) + i];
    float nea = 0.99f * ea_in[i] + 0.01f * es;
    out[EA_OFF + i] = nea;
    out[EMB_OFF + i] = nea / csn[i >> 6];
}

extern "C" void kernel_launch(void* const* d_in, const int* in_sizes, int n_in,
                              void* d_out, int out_size, void* d_ws, size_t ws_size,
                              hipStream_t stream) {
    const float* z   = (const float*)d_in[0];
    const float* emb = (const float*)d_in[1];
    const float* cs  = (const float*)d_in[2];
    const float* ea  = (const float*)d_in[3];
    float* out = (float*)d_out;
    float* ws  = (float*)d_ws;

    // pick slice count that fits the workspace (deterministic for fixed ws_size)
    int ns = 8;
    while (ns > 1) {
        size_t need = (size_t)(64 + ns * NE + (size_t)ns * NE * CDIM
                               + 2 * NE + NE * CDIM) * 4;
        if (need <= ws_size) break;
        ns >>= 1;
    }
    float* ws_loss  = ws;                            // 1 (zeroed)
    float* ws_cntp  = ws + 64;                       // ns*1024
    float* ws_epart = ws_cntp + ns * NE;             // ns*65536
    float* ws_enorm = ws_epart + (size_t)ns * NE * CDIM;  // 1024
    float* ws_csn   = ws_enorm + NE;                 // 1024
    float* ws_embT  = ws_csn + NE;                   // 65536 (embT[c][j])

    hipMemsetAsync(ws_loss, 0, 256, stream);   // loss accumulator only
    k_enorm<<<256, 256, 0, stream>>>(emb, ws_enorm, ws_embT);
    k_fused5<<<1024, 256, 0, stream>>>(z, emb, ws_embT, ws_enorm, out, ws_loss);
    k_scatter<<<ns * 64, 1024, 0, stream>>>(z, out + IDX_OFF, ws_epart, ws_cntp, ns);
    k_cluster<<<1, 1024, 0, stream>>>(cs, ws_cntp, ws_loss, out, ws_csn, ns);
    k_embed<<<256, 256, 0, stream>>>(ea, ws_epart, ws_csn, out, ns);
}